// Round 5
// baseline (352.551 us; speedup 1.0000x reference)
//
#include <hip/hip_runtime.h>
#include <cmath>

#define B_   128
#define H_   256
#define W_   256
#define WC_  129
#define L_   182
#define NG_  33    // column groups per image in pass2 (4 cols/group * 33 >= 129)
#define NH_  16    // histogram slices (16 * 2064 = 33024 = H_*WC_)
#define PI_F 3.14159265358979f

// ---------------------------------------------------------------------------
// Wave-synchronous 256-point DIF FFT across one 64-lane wave.
// Lane l holds 4 complex elements in registers: slot j = x[l + 64*j].
// Output: storage index q = l + 64*j holds X[bitrev8(q)].
// ---------------------------------------------------------------------------
__device__ __forceinline__ void fft256_wave(float vr[4], float vi[4], int l) {
  float c0, s0;
  __sincosf(-2.f * PI_F * (float)l / 256.f, &s0, &c0);  // w0 = W256^l
  {
    float ur = vr[0] + vr[2], ui = vi[0] + vi[2];
    float dr = vr[0] - vr[2], di = vi[0] - vi[2];
    vr[0] = ur; vi[0] = ui;
    vr[2] = dr * c0 - di * s0; vi[2] = dr * s0 + di * c0;
    float c1 = s0, s1 = -c0;
    ur = vr[1] + vr[3]; ui = vi[1] + vi[3];
    dr = vr[1] - vr[3]; di = vi[1] - vi[3];
    vr[1] = ur; vi[1] = ui;
    vr[3] = dr * c1 - di * s1; vi[3] = dr * s1 + di * c1;
  }
  {
    float c2 = c0 * c0 - s0 * s0, s2 = 2.f * c0 * s0;
    float ur = vr[0] + vr[1], ui = vi[0] + vi[1];
    float dr = vr[0] - vr[1], di = vi[0] - vi[1];
    vr[0] = ur; vi[0] = ui;
    vr[1] = dr * c2 - di * s2; vi[1] = dr * s2 + di * c2;
    ur = vr[2] + vr[3]; ui = vi[2] + vi[3];
    dr = vr[2] - vr[3]; di = vi[2] - vi[3];
    vr[2] = ur; vi[2] = ui;
    vr[3] = dr * c2 - di * s2; vi[3] = dr * s2 + di * c2;
  }
  #pragma unroll
  for (int h = 32; h >= 1; h >>= 1) {
    int i = l & (h - 1);
    float c, s;
    __sincosf(-PI_F * (float)i / (float)h, &s, &c);
    bool up = (l & h) != 0;
    float cc = up ? c : 1.f;
    float ss = up ? s : 0.f;
    float sgn = up ? -1.f : 1.f;
    #pragma unroll
    for (int j = 0; j < 4; ++j) {
      float br = __shfl_xor(vr[j], h, 64);
      float bi = __shfl_xor(vi[j], h, 64);
      float tr = fmaf(sgn, vr[j], br);
      float ti = fmaf(sgn, vi[j], bi);
      vr[j] = tr * cc - ti * ss;
      vi[j] = tr * ss + ti * cc;
    }
  }
}

#define P1_PAIRS 16
#define P1_STRIDE 259  // float2 LDS stride breaks pow2 bank pattern

// Pass 1 (r0-verbatim FFT body): luma + row FFT with the two-real-rows-in-one-
// complex-FFT trick. Added: (a) zero bins/done counters (ws is poisoned each
// iter), (b) blocks 0..15 each histogram 1/16th of radius into private LDS and
// plain-store cntp[g][L] — no races, starts first so it hides under pass1.
__global__ __launch_bounds__(1024) void pass1_kernel(
    const float* __restrict__ data, float4* __restrict__ inter4,
    const int* __restrict__ radius, float* __restrict__ cntp,
    float* __restrict__ bins, unsigned* __restrict__ done) {
  __shared__ float2 tile[P1_PAIRS * P1_STRIDE];
  __shared__ float lcnt[L_];
  int tid = threadIdx.x;
  // Zero bins[B_*L_] and done[B_+1] (one store for the first 23296 threads).
  int gidx = blockIdx.x * 1024 + tid;
  if (gidx < B_ * L_) bins[gidx] = 0.f;
  if (gidx < B_ + 1) done[gidx] = 0u;
  // Distributed radius-count histogram (batch-independent).
  if (blockIdx.x < NH_) {
    for (int i = tid; i < L_; i += 1024) lcnt[i] = 0.f;
    __syncthreads();
    int base = (int)blockIdx.x * 2064;
    for (int i = tid; i < 2064; i += 1024)
      atomicAdd(&lcnt[radius[base + i]], 1.f);
    __syncthreads();
    for (int i = tid; i < L_; i += 1024) cntp[blockIdx.x * L_ + i] = lcnt[i];
  }
  int w = tid >> 6, l = tid & 63;
  int b = blockIdx.x >> 3;
  int row0 = (blockIdx.x & 7) * 32;
  int rowA = row0 + 2 * w;
  const float* pA = data + ((size_t)b * 3) * (H_ * W_) + (size_t)rowA * W_;
  float vr[4], vi[4];
  #pragma unroll
  for (int j = 0; j < 4; ++j) {
    int i = l + 64 * j;
    float r = pA[i], g = pA[H_ * W_ + i], bl = pA[2 * H_ * W_ + i];
    vr[j] = fmaf(0.299f, r, fmaf(0.587f, g, 0.114f * bl));
    r = pA[W_ + i]; g = pA[H_ * W_ + W_ + i]; bl = pA[2 * H_ * W_ + W_ + i];
    vi[j] = fmaf(0.299f, r, fmaf(0.587f, g, 0.114f * bl));
  }
  fft256_wave(vr, vi, l);
  #pragma unroll
  for (int j = 0; j < 4; ++j)
    tile[w * P1_STRIDE + l + 64 * j] = make_float2(vr[j], vi[j]);
  __syncthreads();
  // X(k) sits at storage q = bitrev8(k). Unpack via conjugate symmetry:
  //   A(k) = (Z(k)+conj(Z(N-k)))/2 ; B(k) = (Z(k)-conj(Z(N-k)))/(2i)
  for (int f = tid; f < WC_ * P1_PAIRS; f += 1024) {
    int k = f >> 4;
    int p = f & 15;
    int qk  = (int)(__brev((unsigned)k) >> 24);
    int qnk = (int)(__brev((unsigned)((256 - k) & 255)) >> 24);
    float2 Zk  = tile[p * P1_STRIDE + qk];
    float2 Znk = tile[p * P1_STRIDE + qnk];
    float4 o;
    o.x = 0.5f * (Zk.x + Znk.x);   // A.re
    o.y = 0.5f * (Zk.y - Znk.y);   // A.im
    o.z = 0.5f * (Zk.y + Znk.y);   // B.re
    o.w = 0.5f * (Znk.x - Zk.x);   // B.im
    inter4[((((size_t)b * WC_ + k) * H_ + row0) >> 1) + p] = o;
  }
}

// Pass 2 fused to the end: r0's 33x4-column FFT geometry; LDS bins flushed
// via global atomicAdd into bins[b][L]. The last-arriving block per image
// (arrival counter done[b], the r3-validated fence+acq_rel pattern) computes
// that image's loss with one wave; the last image overall (done[B_]) reduces
// the 128 per-sample losses and writes the scalar output.
__global__ __launch_bounds__(256) void pass2_kernel(
    const float2* __restrict__ inter, const int* __restrict__ radius,
    const float* __restrict__ cntp, const float* __restrict__ mean,
    float* __restrict__ bins, unsigned* __restrict__ done,
    float* __restrict__ lpart, float* __restrict__ out) {
  __shared__ float lbins[L_];
  __shared__ int sdone;
  int tid = threadIdx.x;
  int wv = tid >> 6, l = tid & 63;
  int b = blockIdx.x / NG_;
  int g = blockIdx.x - b * NG_;
  int k = g * 4 + wv;
  for (int i = tid; i < L_; i += 256) lbins[i] = 0.f;
  __syncthreads();
  if (k < WC_) {
    const float2* p = inter + ((size_t)b * WC_ + k) * H_;
    float vr[4], vi[4];
    #pragma unroll
    for (int j = 0; j < 4; ++j) {
      float2 v = p[l + 64 * j];
      vr[j] = v.x; vi[j] = v.y;
    }
    fft256_wave(vr, vi, l);
    int rb = 4 * (int)(__brev((unsigned)l) >> 26);
    #pragma unroll
    for (int j = 0; j < 4; ++j) {
      int rf = rb + ((j == 1) ? 2 : (j == 2) ? 1 : j);  // bitrev2(j)
      int bin = radius[rf * WC_ + k];
      float pw = vr[j] * vr[j] + vi[j] * vi[j];
      atomicAdd(&lbins[bin], 20.f * __logf(pw + 1e-8f));
    }
  }
  __syncthreads();
  for (int i = tid; i < L_; i += 256)
    if (lbins[i] != 0.f) atomicAdd(&bins[(size_t)b * L_ + i], lbins[i]);
  __syncthreads();
  if (tid == 0) {
    __threadfence();
    unsigned old = __hip_atomic_fetch_add(&done[b], 1u, __ATOMIC_ACQ_REL,
                                          __HIP_MEMORY_SCOPE_AGENT);
    sdone = (old == (unsigned)(NG_ - 1));
  }
  __syncthreads();
  if (!sdone) return;
  // ------- finisher for image b: wave 0 only (no further __syncthreads) -----
  if (wv != 0) return;
  bool has2 = (l + 128) < L_;
  float n0 = 0.f, n1 = 0.f, n2 = 0.f;
  #pragma unroll 1
  for (int g2 = 0; g2 < NH_; ++g2) {
    n0 += cntp[g2 * L_ + l];
    n1 += cntp[g2 * L_ + l + 64];
    if (has2) n2 += cntp[g2 * L_ + l + 128];
  }
  const float* pb = bins + (size_t)b * L_;
  float s0 = __hip_atomic_load(&pb[l], __ATOMIC_ACQUIRE,
                               __HIP_MEMORY_SCOPE_AGENT);
  float s1 = __hip_atomic_load(&pb[l + 64], __ATOMIC_ACQUIRE,
                               __HIP_MEMORY_SCOPE_AGENT);
  float s2 = has2 ? __hip_atomic_load(&pb[l + 128], __ATOMIC_ACQUIRE,
                                      __HIP_MEMORY_SCOPE_AGENT) : 0.f;
  float pa = s0 / n0;
  float pc = s1 / n1;
  float pe = has2 ? (s2 / n2) : 0.f;
  float mn = fminf(pa, pc);
  if (has2) mn = fminf(mn, pe);
  #pragma unroll
  for (int h = 32; h >= 1; h >>= 1) mn = fminf(mn, __shfl_xor(mn, h, 64));
  float mxr = fmaxf(pa, pc);
  if (has2) mxr = fmaxf(mxr, pe);
  #pragma unroll
  for (int h = 32; h >= 1; h >>= 1) mxr = fmaxf(mxr, __shfl_xor(mxr, h, 64));
  float mx = mxr - mn;  // max(profile - mn): max attained at the same element
  float s = fabsf((pa - mn) / mx - mean[l]) +
            fabsf((pc - mn) / mx - mean[l + 64]);
  if (has2) s += fabsf((pe - mn) / mx - mean[l + 128]);
  #pragma unroll
  for (int h = 32; h >= 1; h >>= 1) s += __shfl_xor(s, h, 64);
  int last = 0;
  if (l == 0) {
    lpart[b] = s;
    __threadfence();
    unsigned old2 = __hip_atomic_fetch_add(&done[B_], 1u, __ATOMIC_ACQ_REL,
                                           __HIP_MEMORY_SCOPE_AGENT);
    last = (old2 == (unsigned)(B_ - 1));
  }
  last = __shfl(last, 0, 64);
  if (last) {
    float v = __hip_atomic_load(&lpart[l], __ATOMIC_ACQUIRE,
                                __HIP_MEMORY_SCOPE_AGENT) +
              __hip_atomic_load(&lpart[l + 64], __ATOMIC_ACQUIRE,
                                __HIP_MEMORY_SCOPE_AGENT);
    #pragma unroll
    for (int h = 32; h >= 1; h >>= 1) v += __shfl_xor(v, h, 64);
    if (l == 0) out[0] = v;
  }
}

extern "C" void kernel_launch(void* const* d_in, const int* in_sizes, int n_in,
                              void* d_out, int out_size, void* d_ws, size_t ws_size,
                              hipStream_t stream) {
  const float* data   = (const float*)d_in[0];  // [128,3,256,256] f32
  const float* mean   = (const float*)d_in[1];  // [182] f32
  const int*   radius = (const int*)d_in[2];    // [256,129] i32
  float* out = (float*)d_out;                   // scalar f32

  float2* inter = (float2*)d_ws;                            // [B][WC][H] complex
  float* bins   = (float*)(inter + (size_t)B_ * WC_ * H_);  // [B][L]
  float* cntp   = bins + (size_t)B_ * L_;                   // [NH][L]
  float* lpart  = cntp + (size_t)NH_ * L_;                  // [B]
  unsigned* done = (unsigned*)(lpart + B_);                 // [B+1]

  pass1_kernel<<<B_ * 8, 1024, 0, stream>>>(data, (float4*)inter, radius,
                                            cntp, bins, done);
  pass2_kernel<<<B_ * NG_, 256, 0, stream>>>(inter, radius, cntp, mean,
                                             bins, done, lpart, out);
}

// Round 6
// 194.582 us; speedup vs baseline: 1.8118x; 1.8118x over previous
//
#include <hip/hip_runtime.h>
#include <cmath>

#define B_   128
#define H_   256
#define W_   256
#define WC_  129
#define L_   182
#define NG_  33    // column groups per image in pass2 (4 cols/group * 33 >= 129)
#define PI_F 3.14159265358979f

// ---------------------------------------------------------------------------
// Wave-synchronous 256-point DIF FFT across one 64-lane wave.
// Lane l holds 4 complex elements in registers: slot j = x[l + 64*j].
// Output: storage index q = l + 64*j holds X[bitrev8(q)].
// ---------------------------------------------------------------------------
__device__ __forceinline__ void fft256_wave(float vr[4], float vi[4], int l) {
  float c0, s0;
  __sincosf(-2.f * PI_F * (float)l / 256.f, &s0, &c0);  // w0 = W256^l
  {
    float ur = vr[0] + vr[2], ui = vi[0] + vi[2];
    float dr = vr[0] - vr[2], di = vi[0] - vi[2];
    vr[0] = ur; vi[0] = ui;
    vr[2] = dr * c0 - di * s0; vi[2] = dr * s0 + di * c0;
    float c1 = s0, s1 = -c0;
    ur = vr[1] + vr[3]; ui = vi[1] + vi[3];
    dr = vr[1] - vr[3]; di = vi[1] - vi[3];
    vr[1] = ur; vi[1] = ui;
    vr[3] = dr * c1 - di * s1; vi[3] = dr * s1 + di * c1;
  }
  {
    float c2 = c0 * c0 - s0 * s0, s2 = 2.f * c0 * s0;
    float ur = vr[0] + vr[1], ui = vi[0] + vi[1];
    float dr = vr[0] - vr[1], di = vi[0] - vi[1];
    vr[0] = ur; vi[0] = ui;
    vr[1] = dr * c2 - di * s2; vi[1] = dr * s2 + di * c2;
    ur = vr[2] + vr[3]; ui = vi[2] + vi[3];
    dr = vr[2] - vr[3]; di = vi[2] - vi[3];
    vr[2] = ur; vi[2] = ui;
    vr[3] = dr * c2 - di * s2; vi[3] = dr * s2 + di * c2;
  }
  #pragma unroll
  for (int h = 32; h >= 1; h >>= 1) {
    int i = l & (h - 1);
    float c, s;
    __sincosf(-PI_F * (float)i / (float)h, &s, &c);
    bool up = (l & h) != 0;
    float cc = up ? c : 1.f;
    float ss = up ? s : 0.f;
    float sgn = up ? -1.f : 1.f;
    #pragma unroll
    for (int j = 0; j < 4; ++j) {
      float br = __shfl_xor(vr[j], h, 64);
      float bi = __shfl_xor(vi[j], h, 64);
      float tr = fmaf(sgn, vr[j], br);
      float ti = fmaf(sgn, vi[j], bi);
      vr[j] = tr * cc - ti * ss;
      vi[j] = tr * ss + ti * cc;
    }
  }
}

// Two interleaved FFTs: FFT A in slots 0..3, FFT B in slots 4..7.
// Shared twiddles (half the sincos), two independent shfl chains for ILP.
__device__ __forceinline__ void fft256x2_wave(float vr[8], float vi[8], int l) {
  float c0, s0;
  __sincosf(-2.f * PI_F * (float)l / 256.f, &s0, &c0);  // W256^l
  float c1 = s0, s1 = -c0;                              // W256^(l+64)
  float c2 = c0 * c0 - s0 * s0, s2 = 2.f * c0 * s0;     // W128^l
  #pragma unroll
  for (int f = 0; f < 8; f += 4) {
    float ur = vr[f+0] + vr[f+2], ui = vi[f+0] + vi[f+2];
    float dr = vr[f+0] - vr[f+2], di = vi[f+0] - vi[f+2];
    vr[f+0] = ur; vi[f+0] = ui;
    vr[f+2] = dr * c0 - di * s0; vi[f+2] = dr * s0 + di * c0;
    ur = vr[f+1] + vr[f+3]; ui = vi[f+1] + vi[f+3];
    dr = vr[f+1] - vr[f+3]; di = vi[f+1] - vi[f+3];
    vr[f+1] = ur; vi[f+1] = ui;
    vr[f+3] = dr * c1 - di * s1; vi[f+3] = dr * s1 + di * c1;
    ur = vr[f+0] + vr[f+1]; ui = vi[f+0] + vi[f+1];
    dr = vr[f+0] - vr[f+1]; di = vi[f+0] - vi[f+1];
    vr[f+0] = ur; vi[f+0] = ui;
    vr[f+1] = dr * c2 - di * s2; vi[f+1] = dr * s2 + di * c2;
    ur = vr[f+2] + vr[f+3]; ui = vi[f+2] + vi[f+3];
    dr = vr[f+2] - vr[f+3]; di = vi[f+2] - vi[f+3];
    vr[f+2] = ur; vi[f+2] = ui;
    vr[f+3] = dr * c2 - di * s2; vi[f+3] = dr * s2 + di * c2;
  }
  #pragma unroll
  for (int h = 32; h >= 1; h >>= 1) {
    int i = l & (h - 1);
    float c, s;
    __sincosf(-PI_F * (float)i / (float)h, &s, &c);
    bool up = (l & h) != 0;
    float cc = up ? c : 1.f;
    float ss = up ? s : 0.f;
    float sgn = up ? -1.f : 1.f;
    #pragma unroll
    for (int j = 0; j < 8; ++j) {
      float br = __shfl_xor(vr[j], h, 64);
      float bi = __shfl_xor(vi[j], h, 64);
      float tr = fmaf(sgn, vr[j], br);
      float ti = fmaf(sgn, vi[j], bi);
      vr[j] = tr * cc - ti * ss;
      vi[j] = tr * ss + ti * cc;
    }
  }
}

#define P1_PAIRS 8
#define P1_STRIDE 259  // float2 LDS stride breaks pow2 bank pattern

// Pass 1 (r3-validated body): luma + row FFT, two-real-rows-in-one-complex-FFT.
// 256-thr blocks (8 blocks/CU at 16.6 KB LDS -> full occupancy, single
// dispatch round of 2048 blocks). float4 global loads (12 dwordx4/thread
// instead of 48 scalar dwords); luma staged via LDS and re-read in the l+64j
// FFT pattern (stride-1, conflict-free).
__global__ __launch_bounds__(256) void pass1_kernel(
    const float* __restrict__ data, float4* __restrict__ inter4) {
  __shared__ float2 tile[P1_PAIRS * P1_STRIDE];  // 16576 B
  float* luma = (float*)tile;                    // 16 rows x 256 = 16384 B alias
  int tid = threadIdx.x;
  int w = tid >> 6, l = tid & 63;
  int b = blockIdx.x >> 4;
  int row0 = (blockIdx.x & 15) * 16;
  const float* base = data + (size_t)b * 3 * (H_ * W_) + (size_t)row0 * W_;
  const float4* pr = (const float4*)base;
  const float4* pg = (const float4*)(base + H_ * W_);
  const float4* pb = (const float4*)(base + 2 * H_ * W_);
  #pragma unroll
  for (int it = 0; it < 4; ++it) {
    int q = tid + 256 * it;          // float4 index into the 16x256 slab
    float4 r = pr[q], g = pg[q], bl = pb[q];
    float4 o;
    o.x = fmaf(0.299f, r.x, fmaf(0.587f, g.x, 0.114f * bl.x));
    o.y = fmaf(0.299f, r.y, fmaf(0.587f, g.y, 0.114f * bl.y));
    o.z = fmaf(0.299f, r.z, fmaf(0.587f, g.z, 0.114f * bl.z));
    o.w = fmaf(0.299f, r.w, fmaf(0.587f, g.w, 0.114f * bl.w));
    ((float4*)luma)[q] = o;
  }
  __syncthreads();
  float vr[8], vi[8];
  #pragma unroll
  for (int f = 0; f < 2; ++f) {
    int rA = 2 * w + 8 * f;          // local row of pair p = w + 4*f
    #pragma unroll
    for (int j = 0; j < 4; ++j) {
      vr[4 * f + j] = luma[rA * W_ + l + 64 * j];
      vi[4 * f + j] = luma[(rA + 1) * W_ + l + 64 * j];
    }
  }
  __syncthreads();  // luma fully consumed; tile may be overwritten
  fft256x2_wave(vr, vi, l);
  #pragma unroll
  for (int j = 0; j < 4; ++j) {
    tile[w * P1_STRIDE + l + 64 * j]       = make_float2(vr[j],     vi[j]);
    tile[(w + 4) * P1_STRIDE + l + 64 * j] = make_float2(vr[4 + j], vi[4 + j]);
  }
  __syncthreads();
  // X(k) sits at storage q = bitrev8(k). Unpack via conjugate symmetry:
  //   A(k) = (Z(k)+conj(Z(N-k)))/2 ; B(k) = (Z(k)-conj(Z(N-k)))/(2i)
  for (int f = tid; f < WC_ * P1_PAIRS; f += 256) {
    int k = f >> 3;
    int p = f & 7;
    int qk  = (int)(__brev((unsigned)k) >> 24);
    int qnk = (int)(__brev((unsigned)((256 - k) & 255)) >> 24);
    float2 Zk  = tile[p * P1_STRIDE + qk];
    float2 Znk = tile[p * P1_STRIDE + qnk];
    float4 o;
    o.x = 0.5f * (Zk.x + Znk.x);   // A.re
    o.y = 0.5f * (Zk.y - Znk.y);   // A.im
    o.z = 0.5f * (Zk.y + Znk.y);   // B.re
    o.w = 0.5f * (Znk.x - Zk.x);   // B.im
    inter4[((((size_t)b * WC_ + k) * H_ + row0) >> 1) + p] = o;
  }
}

// Pass 2 (r0-verbatim): column FFT + log-power + radial binning into
// per-block LDS bins, flushed with plain stores to partial[b][g][L].
// Blocks with b==0 also produce the radial count histogram into cntpart.
__global__ __launch_bounds__(256) void pass2_kernel(
    const float2* __restrict__ inter, const int* __restrict__ radius,
    float* __restrict__ partial, float* __restrict__ cntpart) {
  __shared__ float lbins[L_];
  __shared__ float lcnt[L_];
  int tid = threadIdx.x;
  int wv = tid >> 6, l = tid & 63;
  int b = blockIdx.x / NG_;
  int g = blockIdx.x - b * NG_;
  int k = g * 4 + wv;
  bool do_cnt = (b == 0);
  for (int i = tid; i < L_; i += 256) lbins[i] = 0.f;
  if (do_cnt)
    for (int i = tid; i < L_; i += 256) lcnt[i] = 0.f;
  __syncthreads();
  if (k < WC_) {
    const float2* p = inter + ((size_t)b * WC_ + k) * H_;
    float vr[4], vi[4];
    #pragma unroll
    for (int j = 0; j < 4; ++j) {
      float2 v = p[l + 64 * j];
      vr[j] = v.x; vi[j] = v.y;
    }
    fft256_wave(vr, vi, l);
    int rb = 4 * (int)(__brev((unsigned)l) >> 26);
    #pragma unroll
    for (int j = 0; j < 4; ++j) {
      int rf = rb + ((j == 1) ? 2 : (j == 2) ? 1 : j);  // bitrev2(j)
      int bin = radius[rf * WC_ + k];
      float pw = vr[j] * vr[j] + vi[j] * vi[j];
      float val = 20.f * __logf(pw + 1e-8f);
      atomicAdd(&lbins[bin], val);
      if (do_cnt) atomicAdd(&lcnt[bin], 1.f);
    }
  }
  __syncthreads();
  float* pp = partial + ((size_t)b * NG_ + g) * L_;
  for (int i = tid; i < L_; i += 256) pp[i] = lbins[i];
  if (do_cnt) {
    float* cp = cntpart + (size_t)g * L_;
    for (int i = tid; i < L_; i += 256) cp[i] = lcnt[i];
  }
}

// One block per batch sample (r0-verbatim): reduce 33 value+count partials,
// segment mean, min-max normalize, L1 vs mean. Plain store per-sample loss.
__global__ __launch_bounds__(256) void loss_kernel(
    const float* __restrict__ partial, const float* __restrict__ cntpart,
    const float* __restrict__ mean, float* __restrict__ lpart) {
  int b = blockIdx.x;
  int t = threadIdx.x;
  __shared__ float prof[L_];
  __shared__ float red[256];
  float acc = 0.f, csum = 0.f;
  if (t < L_) {
    const float* pb = partial + (size_t)b * NG_ * L_;
    #pragma unroll 3
    for (int g = 0; g < NG_; ++g) {
      acc  += pb[g * L_ + t];
      csum += cntpart[g * L_ + t];
    }
    prof[t] = acc / csum;
  }
  __syncthreads();
  red[t] = (t < L_) ? prof[t] : INFINITY;
  __syncthreads();
  for (int s = 128; s > 0; s >>= 1) {
    if (t < s) red[t] = fminf(red[t], red[t + s]);
    __syncthreads();
  }
  float mn = red[0];
  __syncthreads();
  red[t] = (t < L_) ? (prof[t] - mn) : -INFINITY;
  __syncthreads();
  for (int s = 128; s > 0; s >>= 1) {
    if (t < s) red[t] = fmaxf(red[t], red[t + s]);
    __syncthreads();
  }
  float mx = red[0];
  __syncthreads();
  red[t] = (t < L_) ? fabsf((prof[t] - mn) / mx - mean[t]) : 0.f;
  __syncthreads();
  for (int s = 128; s > 0; s >>= 1) {
    if (t < s) red[t] += red[t + s];
    __syncthreads();
  }
  if (t == 0) lpart[b] = red[0];
}

// Final: one wave sums the 128 per-sample losses, plain store to out.
__global__ __launch_bounds__(64) void final_kernel(
    const float* __restrict__ lpart, float* __restrict__ out) {
  int l = threadIdx.x;
  float v = lpart[l] + lpart[l + 64];
  #pragma unroll
  for (int h = 32; h >= 1; h >>= 1) v += __shfl_xor(v, h, 64);
  if (l == 0) out[0] = v;
}

extern "C" void kernel_launch(void* const* d_in, const int* in_sizes, int n_in,
                              void* d_out, int out_size, void* d_ws, size_t ws_size,
                              hipStream_t stream) {
  const float* data   = (const float*)d_in[0];  // [128,3,256,256] f32
  const float* mean   = (const float*)d_in[1];  // [182] f32
  const int*   radius = (const int*)d_in[2];    // [256,129] i32
  float* out = (float*)d_out;                   // scalar f32

  float2* inter = (float2*)d_ws;                          // [B][WC][H] complex
  size_t inter_bytes = (size_t)B_ * WC_ * H_ * sizeof(float2);
  float* partial = (float*)((char*)d_ws + inter_bytes);   // [B][NG][L]
  float* cntpart = partial + (size_t)B_ * NG_ * L_;       // [NG][L]
  float* lpart   = cntpart + (size_t)NG_ * L_;            // [B]

  pass1_kernel<<<B_ * 16, 256, 0, stream>>>(data, (float4*)inter);
  pass2_kernel<<<B_ * NG_, 256, 0, stream>>>(inter, radius, partial, cntpart);
  loss_kernel<<<B_, 256, 0, stream>>>(partial, cntpart, mean, lpart);
  final_kernel<<<1, 64, 0, stream>>>(lpart, out);
}